// Round 1
// baseline (28829.510 us; speedup 1.0000x reference)
//
#include <hip/hip_runtime.h>

#define S_LEN 1024
#define B_SZ  64
#define D_IN  512
#define U_SZ  512
#define NWG_DIR 64       // workgroups per direction
#define UNITS_PER_WG 8   // 512 / 64
#define NT 2             // two 16-col MFMA n-tiles (cols = 4 gates x 8 units)
#define KSTEPS 32        // K = 1024 (x:512 + h:512) / 32

typedef __attribute__((ext_vector_type(8))) short short8;
typedef __attribute__((ext_vector_type(4))) float floatx4;

__device__ __forceinline__ unsigned short f2bf(float f) {
  union { float f; unsigned u; } v; v.f = f;
  unsigned r = v.u + 0x7fffu + ((v.u >> 16) & 1u);   // RNE
  return (unsigned short)(r >> 16);
}
__device__ __forceinline__ float fsig(float x) {
  return __builtin_amdgcn_rcpf(1.0f + __expf(-x));
}
__device__ __forceinline__ float ftanh(float x) {
  return 1.0f - 2.0f * __builtin_amdgcn_rcpf(__expf(2.0f * x) + 1.0f);
}

// ---- transpose inputs [B,S,D] f32 -> [S,B,D] bf16 ----
__global__ void xprep_kernel(const float* __restrict__ x,
                             unsigned short* __restrict__ Axt) {
  int bs = blockIdx.x;                 // b*1024 + s
  int b = bs >> 10, s = bs & 1023;
  float4 v = ((const float4*)x)[(size_t)bs * 128 + threadIdx.x];
  ushort4 o;
  o.x = f2bf(v.x); o.y = f2bf(v.y); o.z = f2bf(v.z); o.w = f2bf(v.w);
  ((ushort4*)(Axt + ((size_t)s * B_SZ + b) * D_IN))[threadIdx.x] = o;
}

// ---- pack mask[B,S] (dtype auto-detected) into per-timestep 64-bit masks ----
__global__ void maskpack_kernel(const unsigned int* __restrict__ mraw,
                                unsigned long long* __restrict__ maskbits) {
  int t = blockIdx.x * blockDim.x + threadIdx.x;
  if (t >= S_LEN) return;
  unsigned d0 = mraw[0];               // mask[0][0..3] always true (len>=512)
  unsigned long long bits = 0;
  if (d0 == 1u) {                      // int32 layout
    const int* m = (const int*)mraw;
    for (int b = 0; b < B_SZ; ++b) if (m[b * S_LEN + t]) bits |= 1ull << b;
  } else if (d0 == 0x3f800000u) {      // float layout
    const float* m = (const float*)mraw;
    for (int b = 0; b < B_SZ; ++b) if (m[b * S_LEN + t] != 0.f) bits |= 1ull << b;
  } else {                             // byte/bool layout
    const unsigned char* m = (const unsigned char*)mraw;
    for (int b = 0; b < B_SZ; ++b) if (m[b * S_LEN + t]) bits |= 1ull << b;
  }
  maskbits[t] = bits;
}

// ---- persistent bidirectional LSTM scan ----
// 128 WGs: blocks [0,64) forward, [64,128) backward. Each WG owns 8 units
// for all 64 batches; W(512)+R(512) columns live in LDS as B-fragments.
__global__ __launch_bounds__(256, 1) void lstm_scan_kernel(
    const unsigned short* __restrict__ Axt,
    const float* __restrict__ kernel_f, const float* __restrict__ rkernel_f,
    const float* __restrict__ bias_f,
    const float* __restrict__ kernel_b, const float* __restrict__ rkernel_b,
    const float* __restrict__ bias_b,
    const unsigned long long* __restrict__ maskbits,
    unsigned short* __restrict__ hbuf,   // [2 dir][2 buf][B][U] bf16
    unsigned int* __restrict__ ctrs,     // [2 dir] (256B apart)
    float* __restrict__ out) {
  __shared__ alignas(16) short lds_b[NT * KSTEPS * 64 * 8];   // 64 KiB

  const int tid  = threadIdx.x;
  const int lane = tid & 63;
  const int wv   = tid >> 6;           // wave = M-tile (16 batches)
  const int dir  = blockIdx.x >> 6;
  const int wg   = blockIdx.x & 63;
  const int u0   = wg * UNITS_PER_WG;

  const float* Wk   = dir ? kernel_b  : kernel_f;
  const float* Rk   = dir ? rkernel_b : rkernel_f;
  const float* bias = dir ? bias_b    : bias_f;

  // Fill LDS B-fragments: element (nt,ks,lane,j) = Wcat[k][col],
  // k = ks*32 + (lane>>4)*8 + j  (rows 0..511 = W, 512..1023 = R),
  // col = gate*512 + u0 + du,  gate = nt*2 + ((lane&15)>>3), du = lane&7.
  for (int item = tid; item < NT * KSTEPS * 64; item += 256) {
    int nt = item >> 11;
    int rem = item & 2047;
    int ks = rem >> 6;
    int ln = rem & 63;
    int kbase = ks * 32 + ((ln >> 4) << 3);
    int col16 = ln & 15;
    int gate = nt * 2 + (col16 >> 3);
    int cg = gate * U_SZ + u0 + (col16 & 7);
    short8 v;
#pragma unroll
    for (int j = 0; j < 8; ++j) {
      int k = kbase + j;
      float f = (k < D_IN) ? Wk[(size_t)k * 2048 + cg]
                           : Rk[(size_t)(k - D_IN) * 2048 + cg];
      v[j] = (short)f2bf(f);
    }
    *(short8*)(&lds_b[item * 8]) = v;
  }
  __syncthreads();

  const int du = lane & 7;
  const int u  = u0 + du;
  float bz[4];
#pragma unroll
  for (int g = 0; g < 4; ++g) bz[g] = bias[g * U_SZ + u];

  float c_st[4] = {0.f, 0.f, 0.f, 0.f};
  float h_st[4] = {0.f, 0.f, 0.f, 0.f};

  unsigned short* hb_base = hbuf + (size_t)dir * 2 * B_SZ * U_SZ;
  unsigned int* ctr = ctrs + dir * 64;

  const int mrow  = lane & 15;         // A-row within M-tile
  const int kq    = (lane >> 4) << 3;  // quad k-offset
  const bool active = (lane & 8) == 0; // lanes holding i/g (partner holds f/o)
  const int brow0 = wv * 16 + ((lane >> 4) << 2);

  for (int t = 0; t < S_LEN; ++t) {
    const int sx = dir ? (S_LEN - 1 - t) : t;
    const unsigned short* xs =
        Axt + (size_t)sx * B_SZ * D_IN + (size_t)(wv * 16 + mrow) * D_IN + kq;
    floatx4 acc0 = {0.f, 0.f, 0.f, 0.f};
    floatx4 acc1 = {0.f, 0.f, 0.f, 0.f};

    // x @ W half — independent of h, runs before the sync point
#pragma unroll
    for (int ks = 0; ks < 16; ++ks) {
      short8 a  = *(const short8*)(xs + ks * 32);
      short8 b0 = *(const short8*)(&lds_b[((0 * KSTEPS + ks) * 64 + lane) * 8]);
      short8 b1 = *(const short8*)(&lds_b[((1 * KSTEPS + ks) * 64 + lane) * 8]);
      acc0 = __builtin_amdgcn_mfma_f32_16x16x32_bf16(a, b0, acc0, 0, 0, 0);
      acc1 = __builtin_amdgcn_mfma_f32_16x16x32_bf16(a, b1, acc1, 0, 0, 0);
    }

    const unsigned long long mb = maskbits[sx];   // prefetch before spin

    // wait until all WGs of this direction finished step t-1
    if (t > 0) {
      if (tid == 0) {
        unsigned target = (unsigned)(NWG_DIR * t);
        while (__hip_atomic_load(ctr, __ATOMIC_RELAXED,
                                 __HIP_MEMORY_SCOPE_AGENT) < target)
          __builtin_amdgcn_s_sleep(1);
      }
      __syncthreads();
      __threadfence();                 // acquire: invalidate L1 before h reads
    }

    // h @ R half from double-buffered global h state (bf16)
    const unsigned short* hs = hb_base + (size_t)((t + 1) & 1) * B_SZ * U_SZ +
                               (size_t)(wv * 16 + mrow) * U_SZ + kq;
#pragma unroll
    for (int ks = 0; ks < 16; ++ks) {
      short8 a  = *(const short8*)(hs + ks * 32);
      short8 b0 = *(const short8*)(&lds_b[((0 * KSTEPS + 16 + ks) * 64 + lane) * 8]);
      short8 b1 = *(const short8*)(&lds_b[((1 * KSTEPS + 16 + ks) * 64 + lane) * 8]);
      acc0 = __builtin_amdgcn_mfma_f32_16x16x32_bf16(a, b0, acc0, 0, 0, 0);
      acc1 = __builtin_amdgcn_mfma_f32_16x16x32_bf16(a, b1, acc1, 0, 0, 0);
    }

    // gates: lane holds i (acc0) and g (acc1); partner lane^8 holds f and o
#pragma unroll
    for (int r = 0; r < 4; ++r) {
      float iv = acc0[r];
      float gv = acc1[r];
      float fv = __shfl_xor(iv, 8, 64);
      float ov = __shfl_xor(gv, 8, 64);
      float zi = iv + bz[0], zf = fv + bz[1], zg = gv + bz[2], zo = ov + bz[3];
      float cn = fsig(zf) * c_st[r] + fsig(zi) * ftanh(zg);
      float hn = fsig(zo) * ftanh(cn);
      int b = brow0 + r;
      bool m = (mb >> b) & 1ull;
      c_st[r] = m ? cn : c_st[r];
      h_st[r] = m ? hn : h_st[r];
    }

    if (active) {
      unsigned short* hw = hb_base + (size_t)(t & 1) * B_SZ * U_SZ;
#pragma unroll
      for (int r = 0; r < 4; ++r) {
        int b = brow0 + r;
        out[((size_t)b * S_LEN + sx) * 1024 + dir * U_SZ + u] = h_st[r];
        hw[b * U_SZ + u] = f2bf(h_st[r]);
      }
      if (t == S_LEN - 1) {            // final h, c (post-mask carries)
        float* fin = out + (size_t)B_SZ * S_LEN * 1024 +
                     (size_t)dir * 2 * B_SZ * U_SZ;
#pragma unroll
        for (int r = 0; r < 4; ++r) {
          int b = brow0 + r;
          fin[b * U_SZ + u] = h_st[r];
          fin[B_SZ * U_SZ + b * U_SZ + u] = c_st[r];
        }
      }
    }

    __threadfence();                   // release h writes to agent scope
    __syncthreads();
    if (tid == 0) atomicAdd(ctr, 1u);  // signal step t done
  }
}

extern "C" void kernel_launch(void* const* d_in, const int* in_sizes, int n_in,
                              void* d_out, int out_size, void* d_ws, size_t ws_size,
                              hipStream_t stream) {
  const float* inputs    = (const float*)d_in[0];
  const void*  mask      = d_in[1];
  const float* kernel_f  = (const float*)d_in[2];
  const float* rkernel_f = (const float*)d_in[3];
  const float* bias_f    = (const float*)d_in[4];
  const float* kernel_b  = (const float*)d_in[5];
  const float* rkernel_b = (const float*)d_in[6];
  const float* bias_b    = (const float*)d_in[7];
  float* out = (float*)d_out;

  char* ws = (char*)d_ws;
  unsigned short* Axt = (unsigned short*)ws;              // 67,108,864 B
  size_t off = (size_t)S_LEN * B_SZ * D_IN * 2;
  unsigned short* hbuf = (unsigned short*)(ws + off);     // 262,144 B
  unsigned int* ctrs = (unsigned int*)(ws + off + 262144);          // 512 B
  unsigned long long* maskbits =
      (unsigned long long*)(ws + off + 262144 + 512);     // 8,192 B

  hipMemsetAsync(hbuf, 0, 262144 + 512, stream);          // h state + counters
  maskpack_kernel<<<4, 256, 0, stream>>>((const unsigned int*)mask, maskbits);
  xprep_kernel<<<S_LEN * B_SZ, 128, 0, stream>>>(inputs, Axt);
  lstm_scan_kernel<<<128, 256, 0, stream>>>(Axt, kernel_f, rkernel_f, bias_f,
                                            kernel_b, rkernel_b, bias_b,
                                            maskbits, hbuf, ctrs, out);
}

// Round 2
// 6221.816 us; speedup vs baseline: 4.6336x; 4.6336x over previous
//
#include <hip/hip_runtime.h>

#define S_LEN 1024
#define B_SZ  64
#define D_IN  512
#define U_SZ  512
#define NWG_DIR 64       // workgroups per direction
#define UNITS_PER_WG 8   // 512 / 64
#define NT 2             // two 16-col MFMA n-tiles (cols = 4 gates x 8 units)
#define KSTEPS 32        // K = 1024 (x:512 + h:512) / 32

typedef __attribute__((ext_vector_type(8))) short short8;
typedef __attribute__((ext_vector_type(4))) float floatx4;

union HQ { unsigned long long q[2]; short8 s; };

__device__ __forceinline__ unsigned short f2bf(float f) {
  union { float f; unsigned u; } v; v.f = f;
  unsigned r = v.u + 0x7fffu + ((v.u >> 16) & 1u);   // RNE
  return (unsigned short)(r >> 16);
}
__device__ __forceinline__ float fsig(float x) {
  return __builtin_amdgcn_rcpf(1.0f + __expf(-x));
}
__device__ __forceinline__ float ftanh(float x) {
  return 1.0f - 2.0f * __builtin_amdgcn_rcpf(__expf(2.0f * x) + 1.0f);
}

// ---- transpose inputs [B,S,D] f32 -> [S,B,D] bf16 ----
__global__ void xprep_kernel(const float* __restrict__ x,
                             unsigned short* __restrict__ Axt) {
  int bs = blockIdx.x;                 // b*1024 + s
  int b = bs >> 10, s = bs & 1023;
  float4 v = ((const float4*)x)[(size_t)bs * 128 + threadIdx.x];
  ushort4 o;
  o.x = f2bf(v.x); o.y = f2bf(v.y); o.z = f2bf(v.z); o.w = f2bf(v.w);
  ((ushort4*)(Axt + ((size_t)s * B_SZ + b) * D_IN))[threadIdx.x] = o;
}

// ---- pack mask[B,S] (dtype auto-detected) into per-timestep 64-bit masks ----
__global__ void maskpack_kernel(const unsigned int* __restrict__ mraw,
                                unsigned long long* __restrict__ maskbits) {
  int t = blockIdx.x * blockDim.x + threadIdx.x;
  if (t >= S_LEN) return;
  unsigned d0 = mraw[0];               // mask[0][0..3] always true (len>=512)
  unsigned long long bits = 0;
  if (d0 == 1u) {                      // int32 layout
    const int* m = (const int*)mraw;
    for (int b = 0; b < B_SZ; ++b) if (m[b * S_LEN + t]) bits |= 1ull << b;
  } else if (d0 == 0x3f800000u) {      // float layout
    const float* m = (const float*)mraw;
    for (int b = 0; b < B_SZ; ++b) if (m[b * S_LEN + t] != 0.f) bits |= 1ull << b;
  } else {                             // byte/bool layout
    const unsigned char* m = (const unsigned char*)mraw;
    for (int b = 0; b < B_SZ; ++b) if (m[b * S_LEN + t]) bits |= 1ull << b;
  }
  maskbits[t] = bits;
}

// ---- persistent bidirectional LSTM scan ----
// 128 WGs: blocks [0,64) forward, [64,128) backward. Each WG owns 8 units
// for all 64 batches. Cross-WG h exchange via relaxed AGENT-scope atomics
// (write-through, coherence-point reads) — NO threadfence / cache flushes.
// h layout: [dir][buf][wg_group=u/8][b][u%8] bf16 (16B-contiguous per A-frag).
__global__ __launch_bounds__(256, 1) void lstm_scan_kernel(
    const unsigned short* __restrict__ Axt,
    const float* __restrict__ kernel_f, const float* __restrict__ rkernel_f,
    const float* __restrict__ bias_f,
    const float* __restrict__ kernel_b, const float* __restrict__ rkernel_b,
    const float* __restrict__ bias_b,
    const unsigned long long* __restrict__ maskbits,
    unsigned short* __restrict__ hbuf,   // [2 dir][2 buf][64][64][8] bf16
    unsigned int* __restrict__ ctrs,     // [2 dir] (256B apart)
    float* __restrict__ out) {
  __shared__ alignas(16) short lds_b[NT * KSTEPS * 64 * 8];   // 64 KiB

  const int tid  = threadIdx.x;
  const int lane = tid & 63;
  const int wv   = tid >> 6;           // wave = M-tile (16 batches)
  const int dir  = blockIdx.x >> 6;
  const int wg   = blockIdx.x & 63;
  const int u0   = wg * UNITS_PER_WG;

  const float* Wk   = dir ? kernel_b  : kernel_f;
  const float* Rk   = dir ? rkernel_b : rkernel_f;
  const float* bias = dir ? bias_b    : bias_f;

  // Fill LDS B-fragments: element (nt,ks,lane,j) = Wcat[k][col],
  // k = ks*32 + (lane>>4)*8 + j  (rows 0..511 = W, 512..1023 = R),
  // col = gate*512 + u0 + du,  gate = nt*2 + ((lane&15)>>3), du = lane&7.
  for (int item = tid; item < NT * KSTEPS * 64; item += 256) {
    int nt = item >> 11;
    int rem = item & 2047;
    int ks = rem >> 6;
    int ln = rem & 63;
    int kbase = ks * 32 + ((ln >> 4) << 3);
    int col16 = ln & 15;
    int gate = nt * 2 + (col16 >> 3);
    int cg = gate * U_SZ + u0 + (col16 & 7);
    short8 v;
#pragma unroll
    for (int j = 0; j < 8; ++j) {
      int k = kbase + j;
      float f = (k < D_IN) ? Wk[(size_t)k * 2048 + cg]
                           : Rk[(size_t)(k - D_IN) * 2048 + cg];
      v[j] = (short)f2bf(f);
    }
    *(short8*)(&lds_b[item * 8]) = v;
  }
  __syncthreads();

  const int du = lane & 7;
  const int u  = u0 + du;
  float bz[4];
#pragma unroll
  for (int g = 0; g < 4; ++g) bz[g] = bias[g * U_SZ + u];

  float c_st[4] = {0.f, 0.f, 0.f, 0.f};
  float h_st[4] = {0.f, 0.f, 0.f, 0.f};

  unsigned short* hb_base = hbuf + (size_t)dir * 2 * B_SZ * U_SZ;
  unsigned int* ctr = ctrs + dir * 64;

  const int mrow  = lane & 15;         // A-row within M-tile
  const int kq    = (lane >> 4) << 3;  // quad k-offset
  const bool active = (lane & 8) == 0; // lanes holding i/g (partner holds f/o)
  const int brow0 = wv * 16 + ((lane >> 4) << 2);
  const int brow  = wv * 16 + mrow;

  for (int t = 0; t < S_LEN; ++t) {
    const int sx = dir ? (S_LEN - 1 - t) : t;
    const unsigned short* xs =
        Axt + (size_t)sx * B_SZ * D_IN + (size_t)brow * D_IN + kq;
    floatx4 acc0 = {0.f, 0.f, 0.f, 0.f};
    floatx4 acc1 = {0.f, 0.f, 0.f, 0.f};

    // x @ W half — independent of h, runs before the sync point
#pragma unroll
    for (int ks = 0; ks < 16; ++ks) {
      short8 a  = *(const short8*)(xs + ks * 32);
      short8 b0 = *(const short8*)(&lds_b[((0 * KSTEPS + ks) * 64 + lane) * 8]);
      short8 b1 = *(const short8*)(&lds_b[((1 * KSTEPS + ks) * 64 + lane) * 8]);
      acc0 = __builtin_amdgcn_mfma_f32_16x16x32_bf16(a, b0, acc0, 0, 0, 0);
      acc1 = __builtin_amdgcn_mfma_f32_16x16x32_bf16(a, b1, acc1, 0, 0, 0);
    }

    const unsigned long long mb = maskbits[sx];   // prefetch before spin

    // wait until all WGs of this direction finished step t-1
    if (t > 0) {
      if (tid == 0) {
        unsigned target = (unsigned)(NWG_DIR * t);
        while (__hip_atomic_load(ctr, __ATOMIC_RELAXED,
                                 __HIP_MEMORY_SCOPE_AGENT) < target)
          __builtin_amdgcn_s_sleep(1);
      }
      __syncthreads();                 // no threadfence: agent-scope atomic
    }                                  // loads below read the coherence point

    // h @ R half: agent-scope coherent loads, issued in a batch to pipeline
    const unsigned long long* hr = (const unsigned long long*)(
        hb_base + (size_t)((t + 1) & 1) * B_SZ * U_SZ);
    HQ hq[16];
#pragma unroll
    for (int ks = 0; ks < 16; ++ks) {
      int wgp = ks * 4 + (lane >> 4);
      const unsigned long long* p = hr + (size_t)(wgp * 64 + brow) * 2;
      hq[ks].q[0] = __hip_atomic_load(p, __ATOMIC_RELAXED,
                                      __HIP_MEMORY_SCOPE_AGENT);
      hq[ks].q[1] = __hip_atomic_load(p + 1, __ATOMIC_RELAXED,
                                      __HIP_MEMORY_SCOPE_AGENT);
    }
#pragma unroll
    for (int ks = 0; ks < 16; ++ks) {
      short8 b0 = *(const short8*)(&lds_b[((0 * KSTEPS + 16 + ks) * 64 + lane) * 8]);
      short8 b1 = *(const short8*)(&lds_b[((1 * KSTEPS + 16 + ks) * 64 + lane) * 8]);
      acc0 = __builtin_amdgcn_mfma_f32_16x16x32_bf16(hq[ks].s, b0, acc0, 0, 0, 0);
      acc1 = __builtin_amdgcn_mfma_f32_16x16x32_bf16(hq[ks].s, b1, acc1, 0, 0, 0);
    }

    // gates: lane holds i (acc0) and g (acc1); partner lane^8 holds f and o
#pragma unroll
    for (int r = 0; r < 4; ++r) {
      float iv = acc0[r];
      float gv = acc1[r];
      float fv = __shfl_xor(iv, 8, 64);
      float ov = __shfl_xor(gv, 8, 64);
      float zi = iv + bz[0], zf = fv + bz[1], zg = gv + bz[2], zo = ov + bz[3];
      float cn = fsig(zf) * c_st[r] + fsig(zi) * ftanh(zg);
      float hn = fsig(zo) * ftanh(cn);
      int b = brow0 + r;
      bool m = (mb >> b) & 1ull;
      c_st[r] = m ? cn : c_st[r];
      h_st[r] = m ? hn : h_st[r];
    }

    // publish h (write-through agent-scope dword stores, packed pairs)
    {
      unsigned short* hw = hb_base + (size_t)(t & 1) * B_SZ * U_SZ +
                           (size_t)wg * 512;
#pragma unroll
      for (int r = 0; r < 4; ++r) {
        unsigned hv = f2bf(h_st[r]);
        unsigned pv = (unsigned)__shfl_xor((int)hv, 1, 64);
        unsigned packed = (hv & 0xffffu) | (pv << 16);
        if (active && !(lane & 1)) {
          int b = brow0 + r;
          __hip_atomic_store((unsigned*)(hw + b * 8 + du), packed,
                             __ATOMIC_RELAXED, __HIP_MEMORY_SCOPE_AGENT);
        }
      }
    }

    // release: drain own h stores (write-through => globally visible), signal
    asm volatile("s_waitcnt vmcnt(0)" ::: "memory");
    __syncthreads();
    if (tid == 0)
      __hip_atomic_fetch_add(ctr, 1u, __ATOMIC_RELAXED,
                             __HIP_MEMORY_SCOPE_AGENT);

    // output writes AFTER the signal — off the inter-WG critical path
    if (active) {
#pragma unroll
      for (int r = 0; r < 4; ++r) {
        int b = brow0 + r;
        __builtin_nontemporal_store(
            h_st[r], out + ((size_t)b * S_LEN + sx) * 1024 + dir * U_SZ + u);
      }
      if (t == S_LEN - 1) {            // final h, c (post-mask carries)
        float* fin = out + (size_t)B_SZ * S_LEN * 1024 +
                     (size_t)dir * 2 * B_SZ * U_SZ;
#pragma unroll
        for (int r = 0; r < 4; ++r) {
          int b = brow0 + r;
          fin[b * U_SZ + u] = h_st[r];
          fin[B_SZ * U_SZ + b * U_SZ + u] = c_st[r];
        }
      }
    }
  }
}

extern "C" void kernel_launch(void* const* d_in, const int* in_sizes, int n_in,
                              void* d_out, int out_size, void* d_ws, size_t ws_size,
                              hipStream_t stream) {
  const float* inputs    = (const float*)d_in[0];
  const void*  mask      = d_in[1];
  const float* kernel_f  = (const float*)d_in[2];
  const float* rkernel_f = (const float*)d_in[3];
  const float* bias_f    = (const float*)d_in[4];
  const float* kernel_b  = (const float*)d_in[5];
  const float* rkernel_b = (const float*)d_in[6];
  const float* bias_b    = (const float*)d_in[7];
  float* out = (float*)d_out;

  char* ws = (char*)d_ws;
  unsigned short* Axt = (unsigned short*)ws;              // 67,108,864 B
  size_t off = (size_t)S_LEN * B_SZ * D_IN * 2;
  unsigned short* hbuf = (unsigned short*)(ws + off);     // 262,144 B
  unsigned int* ctrs = (unsigned int*)(ws + off + 262144);          // 512 B
  unsigned long long* maskbits =
      (unsigned long long*)(ws + off + 262144 + 512);     // 8,192 B

  hipMemsetAsync(hbuf, 0, 262144 + 512, stream);          // h state + counters
  maskpack_kernel<<<4, 256, 0, stream>>>((const unsigned int*)mask, maskbits);
  xprep_kernel<<<S_LEN * B_SZ, 128, 0, stream>>>(inputs, Axt);
  lstm_scan_kernel<<<128, 256, 0, stream>>>(Axt, kernel_f, rkernel_f, bias_f,
                                            kernel_b, rkernel_b, bias_b,
                                            maskbits, hbuf, ctrs, out);
}